// Round 17
// baseline (140.474 us; speedup 1.0000x reference)
//
#include <hip/hip_runtime.h>

#define BB   1024
#define TT   512
#define NIN  28
#define NS   4
#define MM   7
#define WW   457          // TT - 28 - 28 + 1
#define SLEN 519
#define EMB  9

#define OUT1_SZ (WW * BB * 144)
#define OUT2_SZ (WW * BB * 28)
#define OUT3_SZ (BB * TT)
#define OUT4_SZ (BB * SLEN)

#define CH   32
#define NCH  (TT / CH)
#define NF2  (WW * BB * 7)

typedef float f4 __attribute__((ext_vector_type(4)));

__device__ __forceinline__ f4 ld4u(const float* p) {
    f4 v;
    __builtin_memcpy(&v, p, sizeof(f4));
    return v;
}

// ---------------------------------------------------------------------------
// Kernel 1: ES scan (R4 version, proven ~10 us).
// ---------------------------------------------------------------------------
__global__ __launch_bounds__(64) void es_scan(const float* __restrict__ Y,
        const int* __restrict__ idxs, const float* __restrict__ EW,
        float* __restrict__ levels, float* __restrict__ seas) {
    __shared__ float yl[64][CH + 1];
    __shared__ float se[64][CH + 1];
    const int tid = threadIdx.x;
    const int b0  = blockIdx.x << 6;
    const int b   = b0 + tid;

    const float* e = EW + idxs[b] * EMB;
    const float lev_sms  = 1.0f / (1.0f + __expf(-e[0]));
    const float seas_sms = 1.0f / (1.0f + __expf(-e[1]));
    const float a_l = 1.0f - lev_sms;
    const float a_s = 1.0f - seas_sms;

    float buf[MM];
    const float is0 = __expf(e[2]);
    {
        float* srow = seas + b * SLEN;
        srow[0] = is0;
#pragma unroll
        for (int k = 1; k < MM; ++k) {
            float v = __expf(e[2 + k]);
            srow[k] = v;
            buf[k - 1] = v;
        }
        buf[MM - 1] = is0;
    }

    f4 pf[8];
#pragma unroll
    for (int k = 0; k < 8; ++k) {
        int flat = (k << 6) + tid;
        int r = flat >> 3, q = flat & 7;
        pf[k] = *reinterpret_cast<const f4*>(Y + (b0 + r) * TT + (q << 2));
    }

    float lev = 0.0f;

#define ES_STEP(TTI)                                                        \
    {                                                                       \
        float y  = yreg[TTI];                                               \
        float st = buf[0];                                                  \
        lev = lev_sms * __fdividef(y, st) + a_l * lev;                      \
        float ns = seas_sms * __fdividef(y, lev) + a_s * st;                \
        buf[0] = buf[1]; buf[1] = buf[2]; buf[2] = buf[3];                  \
        buf[3] = buf[4]; buf[4] = buf[5]; buf[5] = buf[6];                  \
        buf[6] = ns;                                                        \
        yl[tid][TTI] = lev;                                                 \
        se[tid][TTI] = ns;                                                  \
    }

    for (int c = 0; c < NCH; ++c) {
        __syncthreads();
#pragma unroll
        for (int k = 0; k < 8; ++k) {
            int flat = (k << 6) + tid;
            int r = flat >> 3, q = flat & 7;
            float* dst = &yl[r][q << 2];
            dst[0] = pf[k].x; dst[1] = pf[k].y; dst[2] = pf[k].z; dst[3] = pf[k].w;
        }
        __syncthreads();
        if (c < NCH - 1) {
#pragma unroll
            for (int k = 0; k < 8; ++k) {
                int flat = (k << 6) + tid;
                int r = flat >> 3, q = flat & 7;
                pf[k] = *reinterpret_cast<const f4*>(
                    Y + (b0 + r) * TT + (c + 1) * CH + (q << 2));
            }
        }

        float yreg[CH];
#pragma unroll
        for (int tt = 0; tt < CH; ++tt) yreg[tt] = yl[tid][tt];

        if (c == 0) {
            lev = __fdividef(yreg[0], is0);
            yl[tid][0] = lev;
            se[tid][0] = is0;
#pragma unroll
            for (int tt = 1; tt < CH; ++tt) ES_STEP(tt)
        } else {
#pragma unroll
            for (int tt = 0; tt < CH; ++tt) ES_STEP(tt)
        }
        __syncthreads();

#pragma unroll
        for (int k = 0; k < CH; ++k) {
            int flat = (k << 6) + tid;
            int r    = flat >> 5;
            int col  = flat & 31;
            levels[(b0 + r) * TT   + c * CH + col]      = yl[r][col];
            seas  [(b0 + r) * SLEN + MM + c * CH + col] = se[r][col];
        }
    }
#undef ES_STEP
}

// ---------------------------------------------------------------------------
// Kernel 2: precompute LL = log(levels) (with LL[b][0] = 0 sentinel) and
// LYS = log(Y) - log(seas) into d_ws. ~3 us.
// ---------------------------------------------------------------------------
__global__ __launch_bounds__(256) void k_pre(const float* __restrict__ levels,
        const float* __restrict__ seas, const float* __restrict__ Y,
        float* __restrict__ LL, float* __restrict__ LYS) {
    int u  = blockIdx.x * 256 + threadIdx.x;    // f4 index < 131072
    int b  = u >> 7;
    int t4 = (u & 127) << 2;
    f4 lv = *reinterpret_cast<const f4*>(levels + b * TT + t4);
    f4 yv = *reinterpret_cast<const f4*>(Y      + b * TT + t4);
    f4 sv = ld4u(seas + b * SLEN + t4);
    f4 a, c;
    a.x = __logf(lv.x); a.y = __logf(lv.y); a.z = __logf(lv.z); a.w = __logf(lv.w);
    if (t4 == 0) a.x = 0.0f;                     // zero sentinel for k_lys
    c.x = __logf(yv.x) - __logf(sv.x);
    c.y = __logf(yv.y) - __logf(sv.y);
    c.z = __logf(yv.z) - __logf(sv.z);
    c.w = __logf(yv.w) - __logf(sv.w);
    *reinterpret_cast<f4*>(LL  + b * TT + t4) = a;
    *reinterpret_cast<f4*>(LYS + b * TT + t4) = c;
}

// ---------------------------------------------------------------------------
// Kernel 3: out1 cols 0..7 (line-aligned 128B runs). col<7 = log insample
// (LYS - LL), col 7 = X chan0 jj=0 via the LL[b][0]=0 sentinel — every lane
// runs the IDENTICAL sequence: ld4u, ld_b32, 4 sub, nt store, 3 adds.
// PRE=0 fallback computes logs inline (no d_ws).
// ---------------------------------------------------------------------------
template<int PRE>
__global__ __launch_bounds__(512) void k_lys(const float* __restrict__ P1,
        const float* __restrict__ P2, const float* __restrict__ Yg,
        const float* __restrict__ X, f4* __restrict__ out1) {
    const int tid = threadIdx.x;
    if (tid >= 504) return;
    const int w    = blockIdx.x >> 1;
    const int half = blockIdx.x & 1;
    const int colm = tid & 7;                    // 0..7
    const int lane = tid >> 3;                   // 0..62
    int b = (half << 9) + lane;
    const int bend = (half << 9) + 512;
    int off = ((w << 10) + b) * 36 + colm;

    if (PRE) {
        const float* pA = (colm < 7) ? (P2 + b * TT + w + (colm << 2))
                                     : (X + (size_t)(b * 2) * TT + w);
        const int    dA = (colm < 7) ? 63 * TT : 63 * 2 * TT;
        const float* pL = P1 + b * TT + ((colm < 7) ? (w + 27) : 0);
        for (; b < bend; b += 63) {
            f4 a = ld4u(pA);
            float l = *pL;
            f4 v;
            v.x = a.x - l; v.y = a.y - l; v.z = a.z - l; v.w = a.w - l;
            __builtin_nontemporal_store(v, out1 + off);
            pA += dA; pL += 63 * TT; off += 63 * 36;
        }
    } else {
        for (; b < bend; b += 63) {
            f4 v;
            if (colm < 7) {
                int t = w + (colm << 2);
                f4 yv = ld4u(Yg + b * TT + t);
                f4 sv = ld4u(P2 + b * SLEN + t);
                float le = P1[b * TT + w + 27];
                v.x = __logf(__fdividef(yv.x, le * sv.x));
                v.y = __logf(__fdividef(yv.y, le * sv.y));
                v.z = __logf(__fdividef(yv.z, le * sv.z));
                v.w = __logf(__fdividef(yv.w, le * sv.w));
            } else {
                v = ld4u(X + (size_t)(b * 2) * TT + w);
            }
            __builtin_nontemporal_store(v, out1 + off);
            off += 63 * 36;
        }
    }
}

// ---------------------------------------------------------------------------
// Kernel 4: out1 cols 8..35 — PURE COPY, ~4 instr per f4 (ld4u from L2-hot
// X/S, nt store, 2 pointer adds). No LDS, no barriers, class fixed at setup.
// ---------------------------------------------------------------------------
__global__ __launch_bounds__(512) void k_x(const float* __restrict__ X,
        const float* __restrict__ S, f4* __restrict__ out1) {
    const int tid = threadIdx.x;
    if (tid >= 504) return;
    const int w    = blockIdx.x >> 1;
    const int half = blockIdx.x & 1;
    const int colx = tid % 28;                   // 0..27
    const int lane = tid / 28;                   // 0..17
    int b = (half << 9) + lane;
    const int bend = (half << 9) + 512;
    int off = ((w << 10) + b) * 36 + 8 + colx;

    const float* pA;
    int dA;
    if (colx < 13)      { pA = X + (size_t)(2 * b) * TT + w + ((colx + 1) << 2); dA = 18 * 2 * TT; }
    else if (colx < 27) { pA = X + (size_t)(2 * b + 1) * TT + w + ((colx - 13) << 2); dA = 18 * 2 * TT; }
    else                { pA = S + (b << 2); dA = 18 * NS; }

    for (; b < bend; b += 18) {
        f4 v = ld4u(pA);
        __builtin_nontemporal_store(v, out1 + off);
        pA += dA; off += 18 * 36;
    }
}

// ---------------------------------------------------------------------------
// Kernel 5: out2 + out5 (R14 flat dense, nt stores, ~18 us).
// ---------------------------------------------------------------------------
__global__ __launch_bounds__(256) void k_out25(const float* __restrict__ Y,
        const float* __restrict__ mask, f4* __restrict__ out2,
        f4* __restrict__ out5) {
    int i = blockIdx.x * blockDim.x + threadIdx.x;
    const int stride = gridDim.x * blockDim.x;
    for (; i < NF2; i += stride) {
        int wb = i / 7;
        int j  = i - wb * 7;
        int b  = wb & (BB - 1);
        int w  = wb >> 10;
        int base = w + NIN + (j << 2);
        f4 vy = ld4u(Y    + b * TT + base);
        f4 vm = ld4u(mask + b * TT + base);
        __builtin_nontemporal_store(vy, &out2[i]);
        __builtin_nontemporal_store(vm, &out5[i]);
    }
}

extern "C" void kernel_launch(void* const* d_in, const int* in_sizes, int n_in,
                              void* d_out, int out_size, void* d_ws, size_t ws_size,
                              hipStream_t stream) {
    const float* S    = (const float*)d_in[0];
    const float* Y    = (const float*)d_in[1];
    const float* X    = (const float*)d_in[2];
    const int*   idxs = (const int*)d_in[3];
    const float* mask = (const float*)d_in[4];
    const float* EW   = (const float*)d_in[5];

    float* out  = (float*)d_out;
    float* out1 = out;
    float* out2 = out1 + OUT1_SZ;
    float* out3 = out2 + OUT2_SZ;        // levels
    float* out4 = out3 + OUT3_SZ;        // seasonalities
    float* out5 = out4 + OUT4_SZ;        // mask_w

    es_scan<<<16, 64, 0, stream>>>(Y, idxs, EW, out3, out4);

    const size_t need = (size_t)2 * BB * TT * sizeof(float);   // 4 MB
    if (ws_size >= need) {
        float* LL  = (float*)d_ws;
        float* LYS = LL + BB * TT;
        k_pre<<<512, 256, 0, stream>>>(out3, out4, Y, LL, LYS);
        k_lys<1><<<2 * WW, 512, 0, stream>>>(LL, LYS, Y, X, (f4*)out1);
    } else {
        k_lys<0><<<2 * WW, 512, 0, stream>>>(out3, out4, Y, X, (f4*)out1);
    }
    k_x<<<2 * WW, 512, 0, stream>>>(X, S, (f4*)out1);
    k_out25<<<2048, 256, 0, stream>>>(Y, mask, (f4*)out2, (f4*)out5);
}